// Round 11
// baseline (207.941 us; speedup 1.0000x reference)
//
#include <hip/hip_runtime.h>
#include <hip/hip_bf16.h>
#include <stdint.h>

using bf16 = __hip_bfloat16;
typedef __attribute__((ext_vector_type(8))) short short8;
typedef __attribute__((ext_vector_type(4))) float f32x4;

#define BM 128
#define BK 32

// -------- async global->LDS, 16B per lane (m97 pattern) --------
__device__ __forceinline__ void g2lds16(const void* g, void* l) {
    __builtin_amdgcn_global_load_lds(
        (const __attribute__((address_space(1))) void*)g,
        (__attribute__((address_space(3))) void*)l,
        16, 0, 0);
}

template <int N>
__device__ __forceinline__ void s_wait_vmcnt() {
    asm volatile("s_waitcnt vmcnt(%0)" :: "n"(N) : "memory");
}

__device__ __forceinline__ short f2bs(float x) {
    union { bf16 h; short s; } u;
    u.h = __float2bfloat16(x);
    return u.s;
}

// ---- LDS XOR swizzles (conflict-free fragment reads; session-proven) ----
// bf16 panel [rows][32 bf16] = 4 groups/row of 8 bf16 (16B). s=(row>>1)&3.
__device__ __forceinline__ int bswz(int row, int cg) { return cg ^ ((row >> 1) & 3); }
// fp32 tile [rows][32 f32] = 8 groups/row of 4 f32 (16B). s=row&7.
__device__ __forceinline__ int fswz(int row, int cg) { return cg ^ (row & 7); }

// ---- fp32 -> bf16 64x64 tile transpose (+ optional row-major bf16 copy) ----
__global__ __launch_bounds__(256)
void transpose_cvt(const float* __restrict__ src, ushort* __restrict__ dstT,
                   ushort* __restrict__ dstN,
                   int R, int C, long sstride, long dstrideT, long dstrideN)
{
    __shared__ __align__(16) ushort t[64][72];
    const float* s = src + (size_t)blockIdx.z * sstride;
    ushort*      dT = dstT + (size_t)blockIdx.z * dstrideT;
    const int r0 = blockIdx.y * 64, c0 = blockIdx.x * 64;
    const int tid = threadIdx.x;
#pragma unroll
    for (int ii = 0; ii < 4; ++ii) {
        int idx = ii * 256 + tid;
        int r = idx >> 4, c4 = (idx & 15) * 4;
        float4 v = *(const float4*)&s[(size_t)(r0 + r) * C + c0 + c4];
        union { ushort u[4]; uint2 q; } o;
        o.u[0] = (ushort)f2bs(v.x); o.u[1] = (ushort)f2bs(v.y);
        o.u[2] = (ushort)f2bs(v.z); o.u[3] = (ushort)f2bs(v.w);
        *(uint2*)&t[r][c4] = o.q;
        if (dstN) {
            ushort* dN = dstN + (size_t)blockIdx.z * dstrideN;
            *(uint2*)&dN[(size_t)(r0 + r) * C + c0 + c4] = o.q;
        }
    }
    __syncthreads();
#pragma unroll
    for (int ii = 0; ii < 2; ++ii) {
        int idx = ii * 256 + tid;
        int c = idx >> 3, r8 = (idx & 7) * 8;
        union { ushort u[8]; uint4 v; } tmp;
#pragma unroll
        for (int j = 0; j < 8; ++j) tmp.u[j] = t[r8 + j][c];
        *(uint4*)&dT[(size_t)(c0 + c) * R + r0 + r8] = tmp.v;
    }
}

// -------- fp32 -> bf16 flat convert (4 elems/thread) --------
__global__ __launch_bounds__(256)
void cvt_f32_bf16(const float* __restrict__ in, ushort* __restrict__ out, int n4)
{
    int i = blockIdx.x * 256 + threadIdx.x;
    if (i >= n4) return;
    float4 v = ((const float4*)in)[i];
    union { ushort u[4]; uint2 q; } o;
    o.u[0] = (ushort)f2bs(v.x); o.u[1] = (ushort)f2bs(v.y);
    o.u[2] = (ushort)f2bs(v.z); o.u[3] = (ushort)f2bs(v.w);
    ((uint2*)out)[i] = o.q;
}

// ================================================================
// Round 10: 256x256 8-wave 4-phase GEMM (T3+T4+T5 port of the m201
// template). C = A * B^T; A:[M][K], B:[N][K] bf16 row-major k-contig.
// BK=64 as 2 x 32-wide k-panels (keeps proven bswz zero-conflict layout;
// [row][64] would alias banks since 128B row stride = full bank cycle).
// 512 threads = 8 waves (2M x 4N), wave tile 128x64, acc 8x4 f32x4.
// LDS 128KB: [2 buf][2 panel][256r x 32k] for A and B.
// Schedule per K-tile t: vmcnt(0) [exactly tile-t's 8 shots outstanding,
// issued during t-1's phases] + barrier; then 4 phases p (qm=p>>1,kk=p&1):
// {8 ds_read frags; 2 g2lds16 shots of tile t+1 -> buf^1; lgkm(0)+
// sched_barrier; setprio(1) 16 MFMA setprio(0); barrier}.
// WAR: buf^1 holds tile t-1, consumed before the t-boundary barrier.
// MODE 0: bf16 store. 1: fp32 atomicAdd. 2: fp32 store.
// ================================================================
template <int MODE>
__global__ __launch_bounds__(512)
void gemm256(const bf16* __restrict__ A, const bf16* __restrict__ B,
             void* __restrict__ Cv, int M, int N, int K, int kChunks,
             long sA, long sB, long sC)
{
    __shared__ __align__(16) bf16 lA[2][2][256 * 32];
    __shared__ __align__(16) bf16 lB[2][2][256 * 32];

    // ---- XCD-contiguous remap (z-aware; bijective since nwg%8==0) ----
    const int gx = gridDim.x, gy = gridDim.y;
    const int nwg = gx * gy * gridDim.z;
    const int wgid = (blockIdx.z * gy + blockIdx.y) * gx + blockIdx.x;
    const int lid = (wgid & 7) * (nwg >> 3) + (wgid >> 3);
    const int pz = gx * gy;
    const int z = lid / pz;
    const int rem = lid - z * pz;
    const int my = rem / gx;
    const int m0 = my * 256;
    const int n0 = (rem - my * gx) * 256;

    const int batch = z / kChunks;
    const int chunk = z - batch * kChunks;
    const int kLen = K / kChunks;
    const int k0 = chunk * kLen;

    const int tid = threadIdx.x;
    const int lane = tid & 63;
    const int wave = tid >> 6;
    const int wm = wave >> 2, wn = wave & 3;   // 2 x 4 wave grid
    const int ml = lane & 15;
    const int q = lane >> 4;

    // staging pointers: shot sh = kk*2+hh covers panel kk, rows [hh*128,+128)
    // thread -> (row = hh*128 + tid>>2, cg = tid&3), swizzled source.
    const bf16* Ab = A + (size_t)batch * sA;
    const bf16* Bb = B + (size_t)batch * sB;
    const int srow = tid >> 2, scg = tid & 3;
    const bf16* pA[4];
    const bf16* pB[4];
#pragma unroll
    for (int kk = 0; kk < 2; ++kk)
#pragma unroll
        for (int hh = 0; hh < 2; ++hh) {
            int r = hh * 128 + srow;
            long koff = k0 + kk * 32 + 8 * bswz(r, scg);
            pA[kk * 2 + hh] = Ab + (size_t)(m0 + r) * K + koff;
            pB[kk * 2 + hh] = Bb + (size_t)(n0 + r) * K + koff;
        }

    f32x4 acc[8][4] = {};

    auto stageA = [&](int nbuf, int sh) {
        g2lds16(pA[sh], &lA[nbuf][sh >> 1][(sh & 1) * 4096 + tid * 8]);
        pA[sh] += 64;
    };
    auto stageB = [&](int nbuf, int sh) {
        g2lds16(pB[sh], &lB[nbuf][sh >> 1][(sh & 1) * 4096 + tid * 8]);
        pB[sh] += 64;
    };

    const int nk = kLen / 64;        // call sites: 16
    // prologue: stage tile 0 into buf 0 (8 shots)
#pragma unroll
    for (int sh = 0; sh < 4; ++sh) stageA(0, sh);
#pragma unroll
    for (int sh = 0; sh < 4; ++sh) stageB(0, sh);

    for (int t = 0; t < nk; ++t) {
        const int buf = t & 1;
        const int nbuf = buf ^ 1;
        const bool pf = (t + 1 < nk);
        s_wait_vmcnt<0>();               // tile t landed (8 shots, aged >=1 phase)
        __builtin_amdgcn_s_barrier();    // published to all waves
#pragma unroll
        for (int p = 0; p < 4; ++p) {
            const int qm = p >> 1, kk = p & 1;
            short8 af[4], bf[4];
#pragma unroll
            for (int mf = 0; mf < 4; ++mf) {
                int r = wm * 128 + qm * 64 + mf * 16 + ml;
                af[mf] = *(const short8*)&lA[buf][kk][r * 32 + 8 * bswz(r, q)];
            }
#pragma unroll
            for (int nf = 0; nf < 4; ++nf) {
                int r = wn * 64 + nf * 16 + ml;
                bf[nf] = *(const short8*)&lB[buf][kk][r * 32 + 8 * bswz(r, q)];
            }
            if (pf) {                    // 2 prefetch shots of tile t+1
                if (p < 2) { stageA(nbuf, 2 * p); stageA(nbuf, 2 * p + 1); }
                else       { stageB(nbuf, 2 * (p - 2)); stageB(nbuf, 2 * (p - 2) + 1); }
            }
            asm volatile("s_waitcnt lgkmcnt(0)" ::: "memory");
            __builtin_amdgcn_sched_barrier(0);
            __builtin_amdgcn_s_setprio(1);
#pragma unroll
            for (int mf = 0; mf < 4; ++mf)
#pragma unroll
                for (int nf = 0; nf < 4; ++nf)
                    acc[qm * 4 + mf][nf] = __builtin_amdgcn_mfma_f32_16x16x32_bf16(
                        af[mf], bf[nf], acc[qm * 4 + mf][nf], 0, 0, 0);
            __builtin_amdgcn_s_setprio(0);
            __builtin_amdgcn_s_barrier();
        }
    }

    // epilogue: C/D layout col=lane&15, row=(lane>>4)*4+r (m89-verified)
#pragma unroll
    for (int mi = 0; mi < 8; ++mi)
#pragma unroll
        for (int nf = 0; nf < 4; ++nf)
#pragma unroll
            for (int rr = 0; rr < 4; ++rr) {
                int row = m0 + wm * 128 + (mi >> 2) * 64 + (mi & 3) * 16 + q * 4 + rr;
                int col = n0 + wn * 64 + nf * 16 + ml;
                if constexpr (MODE == 1) {
                    float* Cf = (float*)Cv + (size_t)batch * sC;
                    atomicAdd(&Cf[(size_t)row * N + col], acc[mi][nf][rr]);
                } else if constexpr (MODE == 0) {
                    ushort* Cb = (ushort*)Cv + (size_t)batch * sC;
                    Cb[(size_t)row * N + col] = (ushort)f2bs(acc[mi][nf][rr]);
                } else {
                    float* Cf = (float*)Cv + (size_t)batch * sC;
                    Cf[(size_t)row * N + col] = acc[mi][nf][rr];
                }
            }
}

// -------- old 128x64-wave 3-buffer kernel (kept for !bigws step 7) --------
template <int MODE, int A_F32, int NFRAG>
__global__ __launch_bounds__(256)
void gemm_bt(const void* __restrict__ Av, const bf16* __restrict__ B,
             void* __restrict__ Cv, int M, int N, int K, int kChunks,
             long sA, long sB, long sC)
{
    constexpr int BN  = 32 * NFRAG;
    constexpr int BSH = (BN * BK * 2) / (256 * 16);
    constexpr int ASH = A_F32 ? 4 : 2;
    constexpr int L   = ASH + BSH;
    constexpr int ANE = BM * BK * (A_F32 ? 2 : 1);
    constexpr int BNE = BN * BK;
    __shared__ __align__(16) bf16 lA[3][ANE];
    __shared__ __align__(16) bf16 lB[3][BNE];

    const int gx   = gridDim.x, gy = gridDim.y;
    const int nwg  = gx * gy * gridDim.z;
    const int wgid = (blockIdx.z * gy + blockIdx.y) * gx + blockIdx.x;
    const int lid  = (wgid & 7) * (nwg >> 3) + (wgid >> 3);
    const int pz   = gx * gy;
    const int z    = lid / pz;
    const int rem  = lid - z * pz;
    const int my   = rem / gx;
    const int m0   = my * BM;
    const int n0   = (rem - my * gx) * BN;

    const int batch = z / kChunks;
    const int chunk = z - batch * kChunks;
    const int kLen  = K / kChunks;
    const int k0    = chunk * kLen;

    const int tid  = threadIdx.x;
    const int lane = tid & 63;
    const int wave = tid >> 6;
    const int wr   = wave >> 1, wc = wave & 1;
    const int ml   = lane & 15;
    const int q    = lane >> 4;

    const bf16* Bb = B + (size_t)batch * sB;
    const bf16* bp[BSH];
#pragma unroll
    for (int s = 0; s < BSH; ++s) {
        int idx = s * 256 + tid;
        int row = idx >> 2, cg = idx & 3;
        bp[s] = Bb + (size_t)(n0 + row) * K + k0 + 8 * bswz(row, cg);
    }

    const float* a32[4];
    const bf16*  a16[2];
    if constexpr (A_F32) {
        const float* Ab = (const float*)Av + (size_t)batch * sA;
#pragma unroll
        for (int s = 0; s < 4; ++s) {
            int idx = s * 256 + tid;
            int row = idx >> 3, cg = idx & 7;
            a32[s] = Ab + (size_t)(m0 + row) * K + k0 + 4 * fswz(row, cg);
        }
    } else {
        const bf16* Ab = (const bf16*)Av + (size_t)batch * sA;
#pragma unroll
        for (int s = 0; s < 2; ++s) {
            int idx = s * 256 + tid;
            int row = idx >> 2, cg = idx & 3;
            a16[s] = Ab + (size_t)(m0 + row) * K + k0 + 8 * bswz(row, cg);
        }
    }

    f32x4 acc[4][NFRAG] = {};

    auto stage = [&](int buf) {
        if constexpr (A_F32) {
            float* lAf = (float*)lA[buf];
#pragma unroll
            for (int s = 0; s < 4; ++s) {
                g2lds16(a32[s], &lAf[(s * 256 + tid) * 4]);
                a32[s] += BK;
            }
        } else {
#pragma unroll
            for (int s = 0; s < 2; ++s) {
                g2lds16(a16[s], &lA[buf][(s * 256 + tid) * 8]);
                a16[s] += BK;
            }
        }
#pragma unroll
        for (int s = 0; s < BSH; ++s) {
            g2lds16(bp[s], &lB[buf][(s * 256 + tid) * 8]);
            bp[s] += BK;
        }
    };

    auto frags = [&](int buf, short8 (&af)[4], short8 (&bfr)[NFRAG]) {
        const bf16* cA = lA[buf];
        const bf16* cB = lB[buf];
#pragma unroll
        for (int i = 0; i < 4; ++i) {
            const int rA = wr * 64 + i * 16 + ml;
            if constexpr (A_F32) {
                const float* lAf = (const float*)cA;
                float4 x0 = *(const float4*)&lAf[rA * 32 + 4 * fswz(rA, 2 * q)];
                float4 x1 = *(const float4*)&lAf[rA * 32 + 4 * fswz(rA, 2 * q + 1)];
                af[i][0] = f2bs(x0.x); af[i][1] = f2bs(x0.y);
                af[i][2] = f2bs(x0.z); af[i][3] = f2bs(x0.w);
                af[i][4] = f2bs(x1.x); af[i][5] = f2bs(x1.y);
                af[i][6] = f2bs(x1.z); af[i][7] = f2bs(x1.w);
            } else {
                af[i] = *(const short8*)&cA[rA * 32 + 8 * bswz(rA, q)];
            }
        }
#pragma unroll
        for (int j = 0; j < NFRAG; ++j) {
            const int rB = wc * (16 * NFRAG) + j * 16 + ml;
            bfr[j] = *(const short8*)&cB[rB * 32 + 8 * bswz(rB, q)];
        }
    };

    auto mfma = [&](short8 (&af)[4], short8 (&bfr)[NFRAG]) {
#pragma unroll
        for (int mi = 0; mi < 4; ++mi)
#pragma unroll
            for (int nj = 0; nj < NFRAG; ++nj)
                acc[mi][nj] = __builtin_amdgcn_mfma_f32_16x16x32_bf16(
                    af[mi], bfr[nj], acc[mi][nj], 0, 0, 0);
    };

    const int nk = kLen / BK;
    stage(0); stage(1);
    int cur = 0;
    for (int t = 0; t < nk - 2; ++t) {
        s_wait_vmcnt<L>();
        __builtin_amdgcn_s_barrier();
        short8 af_[4], bf_[NFRAG];
        frags(cur, af_, bf_);
        int nb = cur + 2; nb = (nb >= 3) ? nb - 3 : nb;
        stage(nb);
        mfma(af_, bf_);
        asm volatile("s_waitcnt lgkmcnt(0)" ::: "memory");
        cur = (cur == 2) ? 0 : cur + 1;
    }
    {
        s_wait_vmcnt<L>();
        __builtin_amdgcn_s_barrier();
        short8 af_[4], bf_[NFRAG];
        frags(cur, af_, bf_);
        mfma(af_, bf_);
        cur = (cur == 2) ? 0 : cur + 1;
    }
    {
        s_wait_vmcnt<0>();
        __builtin_amdgcn_s_barrier();
        short8 af_[4], bf_[NFRAG];
        frags(cur, af_, bf_);
        mfma(af_, bf_);
    }

#pragma unroll
    for (int mi = 0; mi < 4; ++mi)
#pragma unroll
        for (int nj = 0; nj < NFRAG; ++nj)
#pragma unroll
            for (int r = 0; r < 4; ++r) {
                int row = m0 + wr * 64 + mi * 16 + q * 4 + r;
                int col = n0 + wc * (16 * NFRAG) + nj * 16 + ml;
                if constexpr (MODE == 1) {
                    float* Cf = (float*)Cv + (size_t)batch * sC;
                    atomicAdd(&Cf[(size_t)row * N + col], acc[mi][nj][r]);
                } else if constexpr (MODE == 0) {
                    ushort* Cb = (ushort*)Cv + (size_t)batch * sC;
                    Cb[(size_t)row * N + col] = (ushort)f2bs(acc[mi][nj][r]);
                } else {
                    float* Cf = (float*)Cv + (size_t)batch * sC;
                    Cf[(size_t)row * N + col] = acc[mi][nj][r];
                }
            }
}

// ---------------------------------------------------------------
// fp32 I/O.  O = ((X W^T) X^T) X == X * (W^T (X^T X))   [associative]
//   Gf = Xt * Xt^T   (split-K=4, fp32 atomic, 256^2 8-phase)
//   Gb = bf16(Gf)
//   Mt = Gb * Wt^T   (bf16 store, 256^2)
//   O  = X * Mt^T    (fp32 store, 256^2; A = Xb bf16; fallback old kernel)
// d_out scratch: Xt@0 (16M) | Gf@16M (8M) | Gb@24M (4M) | Wt@28M (2M)
// ws: [Xb bf16 16M if ws_size>=20M] + Mt bf16 4M.
// ---------------------------------------------------------------
extern "C" void kernel_launch(void* const* d_in, const int* in_sizes, int n_in,
                              void* d_out, int out_size, void* d_ws, size_t ws_size,
                              hipStream_t stream)
{
    const int B = 2, N = 4096, D = 1024;
    const float* X = (const float*)d_in[0];   // [B][N][D] fp32
    const float* W = (const float*)d_in[1];   // [D][D]    fp32
    float* out = (float*)d_out;               // [B][N][D] fp32

    char* ob = (char*)d_out;
    char* ws = (char*)d_ws;
    ushort* Xt = (ushort*)ob;                  // [B][D][N] bf16, 16 MiB
    float*  Gf = (float*)(ob + (16ll << 20));  // [B][D][D] fp32,  8 MiB
    ushort* Gb = (ushort*)(ob + (24ll << 20)); // [B][D][D] bf16,  4 MiB
    ushort* Wt = (ushort*)(ob + (28ll << 20)); // [D][D]    bf16,  2 MiB

    const bool bigws = ws_size >= (20ull << 20);
    ushort* Xb = bigws ? (ushort*)ws : nullptr;             // [B][N][D] bf16
    ushort* Mt = (ushort*)(ws + (bigws ? (16ll << 20) : 0)); // [B][D][D] bf16

    // 1) Xt[b] = bf16(X[b])^T  (+ Xb = bf16(X) row-major when ws allows)
    transpose_cvt<<<dim3(D / 64, N / 64, B), 256, 0, stream>>>(
        X, Xt, Xb, N, D, (long)N * D, (long)D * N, (long)N * D);
    // 2) Wt = bf16(W)^T
    transpose_cvt<<<dim3(D / 64, D / 64, 1), 256, 0, stream>>>(
        W, Wt, nullptr, D, D, 0, 0, 0);
    // 3) zero split-K accumulator
    (void)hipMemsetAsync(Gf, 0, (size_t)B * D * D * sizeof(float), stream);
    // 4) Gf[b] += Xt[b] * Xt[b]^T  (M=N=D, K=4096, sk=4; 128 blocks)
    gemm256<1><<<dim3(D / 256, D / 256, B * 4), 512, 0, stream>>>(
        (const bf16*)Xt, (const bf16*)Xt, Gf, D, D, N, 4,
        (long)D * N, (long)D * N, (long)D * D);
    // 5) Gb = bf16(Gf)
    cvt_f32_bf16<<<dim3(B * D * D / 4 / 256), 256, 0, stream>>>(
        Gf, Gb, B * D * D / 4);
    // 6) Mt[b] = Gb[b] * Wt^T  (M=N=K=D; 32 blocks)
    gemm256<0><<<dim3(D / 256, D / 256, B), 512, 0, stream>>>(
        (const bf16*)Gb, (const bf16*)Wt, Mt, D, D, D, 1,
        (long)D * D, 0, (long)D * D);
    // 7) O[b] = X[b] * Mt[b]^T  (M=4096, N=D, K=D; 128 blocks)
    if (bigws) {
        gemm256<2><<<dim3(D / 256, N / 256, B), 512, 0, stream>>>(
            (const bf16*)Xb, (const bf16*)Mt, out, N, D, D, 1,
            (long)N * D, (long)D * D, (long)N * D);
    } else {
        gemm_bt<2, 1, 2><<<dim3(D / 64, N / BM, B), 256, 0, stream>>>(
            (const void*)X, (const bf16*)Mt, out, N, D, D, 1,
            (long)N * D, (long)D * D, (long)N * D);
    }
}

// Round 12
// 207.252 us; speedup vs baseline: 1.0033x; 1.0033x over previous
//
#include <hip/hip_runtime.h>
#include <hip/hip_bf16.h>
#include <stdint.h>

using bf16 = __hip_bfloat16;
typedef __attribute__((ext_vector_type(8))) short short8;
typedef __attribute__((ext_vector_type(4))) float f32x4;

#define BM 128
#define BK 32

// -------- async global->LDS, 16B per lane (m97 pattern) --------
__device__ __forceinline__ void g2lds16(const void* g, void* l) {
    __builtin_amdgcn_global_load_lds(
        (const __attribute__((address_space(1))) void*)g,
        (__attribute__((address_space(3))) void*)l,
        16, 0, 0);
}

template <int N>
__device__ __forceinline__ void s_wait_vmcnt() {
    asm volatile("s_waitcnt vmcnt(%0)" :: "n"(N) : "memory");
}

__device__ __forceinline__ short f2bs(float x) {
    union { bf16 h; short s; } u;
    u.h = __float2bfloat16(x);
    return u.s;
}

// ---- LDS XOR swizzles (conflict-free fragment reads; session-proven) ----
// bf16 panel [rows][32 bf16] = 4 groups/row of 8 bf16 (16B). s=(row>>1)&3.
__device__ __forceinline__ int bswz(int row, int cg) { return cg ^ ((row >> 1) & 3); }
// fp32 tile [rows][32 f32] = 8 groups/row of 4 f32 (16B). s=row&7.
__device__ __forceinline__ int fswz(int row, int cg) { return cg ^ (row & 7); }

// ---- fp32 -> bf16 64x64 tile transpose (+ optional row-major bf16 copy) ----
__global__ __launch_bounds__(256)
void transpose_cvt(const float* __restrict__ src, ushort* __restrict__ dstT,
                   ushort* __restrict__ dstN,
                   int R, int C, long sstride, long dstrideT, long dstrideN)
{
    __shared__ __align__(16) ushort t[64][72];
    const float* s = src + (size_t)blockIdx.z * sstride;
    ushort*      dT = dstT + (size_t)blockIdx.z * dstrideT;
    const int r0 = blockIdx.y * 64, c0 = blockIdx.x * 64;
    const int tid = threadIdx.x;
#pragma unroll
    for (int ii = 0; ii < 4; ++ii) {
        int idx = ii * 256 + tid;
        int r = idx >> 4, c4 = (idx & 15) * 4;
        float4 v = *(const float4*)&s[(size_t)(r0 + r) * C + c0 + c4];
        union { ushort u[4]; uint2 q; } o;
        o.u[0] = (ushort)f2bs(v.x); o.u[1] = (ushort)f2bs(v.y);
        o.u[2] = (ushort)f2bs(v.z); o.u[3] = (ushort)f2bs(v.w);
        *(uint2*)&t[r][c4] = o.q;
        if (dstN) {
            ushort* dN = dstN + (size_t)blockIdx.z * dstrideN;
            *(uint2*)&dN[(size_t)(r0 + r) * C + c0 + c4] = o.q;
        }
    }
    __syncthreads();
#pragma unroll
    for (int ii = 0; ii < 2; ++ii) {
        int idx = ii * 256 + tid;
        int c = idx >> 3, r8 = (idx & 7) * 8;
        union { ushort u[8]; uint4 v; } tmp;
#pragma unroll
        for (int j = 0; j < 8; ++j) tmp.u[j] = t[r8 + j][c];
        *(uint4*)&dT[(size_t)(c0 + c) * R + r0 + r8] = tmp.v;
    }
}

// -------- fp32 -> bf16 flat convert (4 elems/thread) --------
__global__ __launch_bounds__(256)
void cvt_f32_bf16(const float* __restrict__ in, ushort* __restrict__ out, int n4)
{
    int i = blockIdx.x * 256 + threadIdx.x;
    if (i >= n4) return;
    float4 v = ((const float4*)in)[i];
    union { ushort u[4]; uint2 q; } o;
    o.u[0] = (ushort)f2bs(v.x); o.u[1] = (ushort)f2bs(v.y);
    o.u[2] = (ushort)f2bs(v.z); o.u[3] = (ushort)f2bs(v.w);
    ((uint2*)out)[i] = o.q;
}

// ================================================================
// Round 11: 256x256 8-wave GEMM, BK=32, 3 LDS buffers, TRUE counted
// vmcnt (T4): boundary wait is vmcnt(4) — tile t's 4 shots (aged 2 full
// tiles) retired, t+1's 4 still in flight. NEVER 0 until the last tile.
// Per tile: 2 phases (qm halves). Phase0: read 4 B-frags (reused) +
// 4 A-frags(qm0), issue tile t+2's 2 A-shots, lgkm0+sched_barrier,
// setprio(1) 16 MFMA setprio(0), barrier. Phase1: 4 A-frags(qm1),
// t+2's 2 B-shots, lgkm0, 16 MFMA. 2 barriers/tile.
// WAR: tile t+2 overwrites buf of t-1; its readers' lgkm0 precedes
// boundary barrier t. In-flight order per wave: [tA,tA,tB,tB] per tile.
// MODE 0: bf16 store. 1: fp32 atomicAdd. 2: fp32 store. nk>=2.
// ================================================================
template <int MODE>
__global__ __launch_bounds__(512)
void gemm256(const bf16* __restrict__ A, const bf16* __restrict__ B,
             void* __restrict__ Cv, int M, int N, int K, int kChunks,
             long sA, long sB, long sC)
{
    __shared__ __align__(16) bf16 lA[3][256 * 32];
    __shared__ __align__(16) bf16 lB[3][256 * 32];

    // ---- XCD-contiguous remap (z-aware; bijective since nwg%8==0) ----
    const int gx = gridDim.x, gy = gridDim.y;
    const int nwg = gx * gy * gridDim.z;
    const int wgid = (blockIdx.z * gy + blockIdx.y) * gx + blockIdx.x;
    const int lid = (wgid & 7) * (nwg >> 3) + (wgid >> 3);
    const int pz = gx * gy;
    const int z = lid / pz;
    const int rem = lid - z * pz;
    const int my = rem / gx;
    const int m0 = my * 256;
    const int n0 = (rem - my * gx) * 256;

    const int batch = z / kChunks;
    const int chunk = z - batch * kChunks;
    const int kLen = K / kChunks;
    const int k0 = chunk * kLen;

    const int tid = threadIdx.x;
    const int lane = tid & 63;
    const int wave = tid >> 6;
    const int wm = wave >> 2, wn = wave & 3;   // 2 x 4 wave grid
    const int ml = lane & 15;
    const int q = lane >> 4;

    // staging: shot sh covers rows [sh*128,+128), 4 threads/row (cg 0..3),
    // pre-swizzled global source, linear LDS dest (16B/thread).
    const bf16* Ab = A + (size_t)batch * sA;
    const bf16* Bb = B + (size_t)batch * sB;
    const int srow = tid >> 2, scg = tid & 3;
    const bf16* pA[2];
    const bf16* pB[2];
#pragma unroll
    for (int sh = 0; sh < 2; ++sh) {
        int r = sh * 128 + srow;
        long koff = k0 + 8 * bswz(r, scg);
        pA[sh] = Ab + (size_t)(m0 + r) * K + koff;
        pB[sh] = Bb + (size_t)(n0 + r) * K + koff;
    }

    auto stageA = [&](int nb) {
#pragma unroll
        for (int sh = 0; sh < 2; ++sh) {
            g2lds16(pA[sh], &lA[nb][sh * 4096 + tid * 8]);
            pA[sh] += BK;
        }
    };
    auto stageB = [&](int nb) {
#pragma unroll
        for (int sh = 0; sh < 2; ++sh) {
            g2lds16(pB[sh], &lB[nb][sh * 4096 + tid * 8]);
            pB[sh] += BK;
        }
    };

    f32x4 acc[8][4] = {};

    const int nk = kLen / BK;        // call sites: 32
    stageA(0); stageB(0);            // tile 0
    stageA(1); stageB(1);            // tile 1 (8 shots in flight)
    int cur = 0;
    for (int t = 0; t < nk; ++t) {
        if (t + 1 < nk) s_wait_vmcnt<4>();   // tile t landed; t+1 in flight
        else            s_wait_vmcnt<0>();   // last tile
        __builtin_amdgcn_s_barrier();
        int nb = cur + 2; if (nb >= 3) nb -= 3;
        const bool pf = (t + 2 < nk);

        // ---- phase 0: B-frags (shared) + A-frags qm=0 ----
        short8 bf[4], af[4];
#pragma unroll
        for (int nf = 0; nf < 4; ++nf) {
            int r = wn * 64 + nf * 16 + ml;
            bf[nf] = *(const short8*)&lB[cur][r * 32 + 8 * bswz(r, q)];
        }
#pragma unroll
        for (int mf = 0; mf < 4; ++mf) {
            int r = wm * 128 + mf * 16 + ml;
            af[mf] = *(const short8*)&lA[cur][r * 32 + 8 * bswz(r, q)];
        }
        if (pf) stageA(nb);                  // tile t+2 A-shots
        asm volatile("s_waitcnt lgkmcnt(0)" ::: "memory");
        __builtin_amdgcn_sched_barrier(0);
        __builtin_amdgcn_s_setprio(1);
#pragma unroll
        for (int mf = 0; mf < 4; ++mf)
#pragma unroll
            for (int nf = 0; nf < 4; ++nf)
                acc[mf][nf] = __builtin_amdgcn_mfma_f32_16x16x32_bf16(
                    af[mf], bf[nf], acc[mf][nf], 0, 0, 0);
        __builtin_amdgcn_s_setprio(0);
        __builtin_amdgcn_s_barrier();

        // ---- phase 1: A-frags qm=1 (B-frags reused) ----
#pragma unroll
        for (int mf = 0; mf < 4; ++mf) {
            int r = wm * 128 + 64 + mf * 16 + ml;
            af[mf] = *(const short8*)&lA[cur][r * 32 + 8 * bswz(r, q)];
        }
        if (pf) stageB(nb);                  // tile t+2 B-shots
        asm volatile("s_waitcnt lgkmcnt(0)" ::: "memory");
        __builtin_amdgcn_sched_barrier(0);
        __builtin_amdgcn_s_setprio(1);
#pragma unroll
        for (int mf = 0; mf < 4; ++mf)
#pragma unroll
            for (int nf = 0; nf < 4; ++nf)
                acc[4 + mf][nf] = __builtin_amdgcn_mfma_f32_16x16x32_bf16(
                    af[mf], bf[nf], acc[4 + mf][nf], 0, 0, 0);
        __builtin_amdgcn_s_setprio(0);

        cur = cur + 1; if (cur >= 3) cur = 0;
    }

    // epilogue: C/D layout col=lane&15, row=(lane>>4)*4+r (m89-verified)
#pragma unroll
    for (int mi = 0; mi < 8; ++mi)
#pragma unroll
        for (int nf = 0; nf < 4; ++nf)
#pragma unroll
            for (int rr = 0; rr < 4; ++rr) {
                int row = m0 + wm * 128 + (mi >> 2) * 64 + (mi & 3) * 16 + q * 4 + rr;
                int col = n0 + wn * 64 + nf * 16 + ml;
                if constexpr (MODE == 1) {
                    float* Cf = (float*)Cv + (size_t)batch * sC;
                    atomicAdd(&Cf[(size_t)row * N + col], acc[mi][nf][rr]);
                } else if constexpr (MODE == 0) {
                    ushort* Cb = (ushort*)Cv + (size_t)batch * sC;
                    Cb[(size_t)row * N + col] = (ushort)f2bs(acc[mi][nf][rr]);
                } else {
                    float* Cf = (float*)Cv + (size_t)batch * sC;
                    Cf[(size_t)row * N + col] = acc[mi][nf][rr];
                }
            }
}

// -------- old 128x64-wave 3-buffer kernel (kept for !bigws step 7) --------
template <int MODE, int A_F32, int NFRAG>
__global__ __launch_bounds__(256)
void gemm_bt(const void* __restrict__ Av, const bf16* __restrict__ B,
             void* __restrict__ Cv, int M, int N, int K, int kChunks,
             long sA, long sB, long sC)
{
    constexpr int BN  = 32 * NFRAG;
    constexpr int BSH = (BN * BK * 2) / (256 * 16);
    constexpr int ASH = A_F32 ? 4 : 2;
    constexpr int L   = ASH + BSH;
    constexpr int ANE = BM * BK * (A_F32 ? 2 : 1);
    constexpr int BNE = BN * BK;
    __shared__ __align__(16) bf16 lA[3][ANE];
    __shared__ __align__(16) bf16 lB[3][BNE];

    const int gx   = gridDim.x, gy = gridDim.y;
    const int nwg  = gx * gy * gridDim.z;
    const int wgid = (blockIdx.z * gy + blockIdx.y) * gx + blockIdx.x;
    const int lid  = (wgid & 7) * (nwg >> 3) + (wgid >> 3);
    const int pz   = gx * gy;
    const int z    = lid / pz;
    const int rem  = lid - z * pz;
    const int my   = rem / gx;
    const int m0   = my * BM;
    const int n0   = (rem - my * gx) * BN;

    const int batch = z / kChunks;
    const int chunk = z - batch * kChunks;
    const int kLen  = K / kChunks;
    const int k0    = chunk * kLen;

    const int tid  = threadIdx.x;
    const int lane = tid & 63;
    const int wave = tid >> 6;
    const int wr   = wave >> 1, wc = wave & 1;
    const int ml   = lane & 15;
    const int q    = lane >> 4;

    const bf16* Bb = B + (size_t)batch * sB;
    const bf16* bp[BSH];
#pragma unroll
    for (int s = 0; s < BSH; ++s) {
        int idx = s * 256 + tid;
        int row = idx >> 2, cg = idx & 3;
        bp[s] = Bb + (size_t)(n0 + row) * K + k0 + 8 * bswz(row, cg);
    }

    const float* a32[4];
    const bf16*  a16[2];
    if constexpr (A_F32) {
        const float* Ab = (const float*)Av + (size_t)batch * sA;
#pragma unroll
        for (int s = 0; s < 4; ++s) {
            int idx = s * 256 + tid;
            int row = idx >> 3, cg = idx & 7;
            a32[s] = Ab + (size_t)(m0 + row) * K + k0 + 4 * fswz(row, cg);
        }
    } else {
        const bf16* Ab = (const bf16*)Av + (size_t)batch * sA;
#pragma unroll
        for (int s = 0; s < 2; ++s) {
            int idx = s * 256 + tid;
            int row = idx >> 2, cg = idx & 3;
            a16[s] = Ab + (size_t)(m0 + row) * K + k0 + 8 * bswz(row, cg);
        }
    }

    f32x4 acc[4][NFRAG] = {};

    auto stage = [&](int buf) {
        if constexpr (A_F32) {
            float* lAf = (float*)lA[buf];
#pragma unroll
            for (int s = 0; s < 4; ++s) {
                g2lds16(a32[s], &lAf[(s * 256 + tid) * 4]);
                a32[s] += BK;
            }
        } else {
#pragma unroll
            for (int s = 0; s < 2; ++s) {
                g2lds16(a16[s], &lA[buf][(s * 256 + tid) * 8]);
                a16[s] += BK;
            }
        }
#pragma unroll
        for (int s = 0; s < BSH; ++s) {
            g2lds16(bp[s], &lB[buf][(s * 256 + tid) * 8]);
            bp[s] += BK;
        }
    };

    auto frags = [&](int buf, short8 (&af)[4], short8 (&bfr)[NFRAG]) {
        const bf16* cA = lA[buf];
        const bf16* cB = lB[buf];
#pragma unroll
        for (int i = 0; i < 4; ++i) {
            const int rA = wr * 64 + i * 16 + ml;
            if constexpr (A_F32) {
                const float* lAf = (const float*)cA;
                float4 x0 = *(const float4*)&lAf[rA * 32 + 4 * fswz(rA, 2 * q)];
                float4 x1 = *(const float4*)&lAf[rA * 32 + 4 * fswz(rA, 2 * q + 1)];
                af[i][0] = f2bs(x0.x); af[i][1] = f2bs(x0.y);
                af[i][2] = f2bs(x0.z); af[i][3] = f2bs(x0.w);
                af[i][4] = f2bs(x1.x); af[i][5] = f2bs(x1.y);
                af[i][6] = f2bs(x1.z); af[i][7] = f2bs(x1.w);
            } else {
                af[i] = *(const short8*)&cA[rA * 32 + 8 * bswz(rA, q)];
            }
        }
#pragma unroll
        for (int j = 0; j < NFRAG; ++j) {
            const int rB = wc * (16 * NFRAG) + j * 16 + ml;
            bfr[j] = *(const short8*)&cB[rB * 32 + 8 * bswz(rB, q)];
        }
    };

    auto mfma = [&](short8 (&af)[4], short8 (&bfr)[NFRAG]) {
#pragma unroll
        for (int mi = 0; mi < 4; ++mi)
#pragma unroll
            for (int nj = 0; nj < NFRAG; ++nj)
                acc[mi][nj] = __builtin_amdgcn_mfma_f32_16x16x32_bf16(
                    af[mi], bfr[nj], acc[mi][nj], 0, 0, 0);
    };

    const int nk = kLen / BK;
    stage(0); stage(1);
    int cur = 0;
    for (int t = 0; t < nk - 2; ++t) {
        s_wait_vmcnt<L>();
        __builtin_amdgcn_s_barrier();
        short8 af_[4], bf_[NFRAG];
        frags(cur, af_, bf_);
        int nb = cur + 2; nb = (nb >= 3) ? nb - 3 : nb;
        stage(nb);
        mfma(af_, bf_);
        asm volatile("s_waitcnt lgkmcnt(0)" ::: "memory");
        cur = (cur == 2) ? 0 : cur + 1;
    }
    {
        s_wait_vmcnt<L>();
        __builtin_amdgcn_s_barrier();
        short8 af_[4], bf_[NFRAG];
        frags(cur, af_, bf_);
        mfma(af_, bf_);
        cur = (cur == 2) ? 0 : cur + 1;
    }
    {
        s_wait_vmcnt<0>();
        __builtin_amdgcn_s_barrier();
        short8 af_[4], bf_[NFRAG];
        frags(cur, af_, bf_);
        mfma(af_, bf_);
    }

#pragma unroll
    for (int mi = 0; mi < 4; ++mi)
#pragma unroll
        for (int nj = 0; nj < NFRAG; ++nj)
#pragma unroll
            for (int r = 0; r < 4; ++r) {
                int row = m0 + wr * 64 + mi * 16 + q * 4 + r;
                int col = n0 + wc * (16 * NFRAG) + nj * 16 + ml;
                if constexpr (MODE == 1) {
                    float* Cf = (float*)Cv + (size_t)batch * sC;
                    atomicAdd(&Cf[(size_t)row * N + col], acc[mi][nj][r]);
                } else if constexpr (MODE == 0) {
                    ushort* Cb = (ushort*)Cv + (size_t)batch * sC;
                    Cb[(size_t)row * N + col] = (ushort)f2bs(acc[mi][nj][r]);
                } else {
                    float* Cf = (float*)Cv + (size_t)batch * sC;
                    Cf[(size_t)row * N + col] = acc[mi][nj][r];
                }
            }
}

// ---------------------------------------------------------------
// fp32 I/O.  O = ((X W^T) X^T) X == X * (W^T (X^T X))   [associative]
//   Gf = Xt * Xt^T   (split-K=4, fp32 atomic, 256^2 counted-vmcnt)
//   Gb = bf16(Gf)
//   Mt = Gb * Wt^T   (bf16 store, 256^2)
//   O  = X * Mt^T    (fp32 store, 256^2; !bigws falls back to gemm_bt)
// d_out scratch: Xt@0 (16M) | Gf@16M (8M) | Gb@24M (4M) | Wt@28M (2M)
// ws: [Xb bf16 16M if ws_size>=20M] + Mt bf16 4M.
// ---------------------------------------------------------------
extern "C" void kernel_launch(void* const* d_in, const int* in_sizes, int n_in,
                              void* d_out, int out_size, void* d_ws, size_t ws_size,
                              hipStream_t stream)
{
    const int B = 2, N = 4096, D = 1024;
    const float* X = (const float*)d_in[0];   // [B][N][D] fp32
    const float* W = (const float*)d_in[1];   // [D][D]    fp32
    float* out = (float*)d_out;               // [B][N][D] fp32

    char* ob = (char*)d_out;
    char* ws = (char*)d_ws;
    ushort* Xt = (ushort*)ob;                  // [B][D][N] bf16, 16 MiB
    float*  Gf = (float*)(ob + (16ll << 20));  // [B][D][D] fp32,  8 MiB
    ushort* Gb = (ushort*)(ob + (24ll << 20)); // [B][D][D] bf16,  4 MiB
    ushort* Wt = (ushort*)(ob + (28ll << 20)); // [D][D]    bf16,  2 MiB

    const bool bigws = ws_size >= (20ull << 20);
    ushort* Xb = bigws ? (ushort*)ws : nullptr;             // [B][N][D] bf16
    ushort* Mt = (ushort*)(ws + (bigws ? (16ll << 20) : 0)); // [B][D][D] bf16

    // 1) Xt[b] = bf16(X[b])^T  (+ Xb = bf16(X) row-major when ws allows)
    transpose_cvt<<<dim3(D / 64, N / 64, B), 256, 0, stream>>>(
        X, Xt, Xb, N, D, (long)N * D, (long)D * N, (long)N * D);
    // 2) Wt = bf16(W)^T
    transpose_cvt<<<dim3(D / 64, D / 64, 1), 256, 0, stream>>>(
        W, Wt, nullptr, D, D, 0, 0, 0);
    // 3) zero split-K accumulator
    (void)hipMemsetAsync(Gf, 0, (size_t)B * D * D * sizeof(float), stream);
    // 4) Gf[b] += Xt[b] * Xt[b]^T  (M=N=D, K=4096, sk=4; 128 blocks, nk=32)
    gemm256<1><<<dim3(D / 256, D / 256, B * 4), 512, 0, stream>>>(
        (const bf16*)Xt, (const bf16*)Xt, Gf, D, D, N, 4,
        (long)D * N, (long)D * N, (long)D * D);
    // 5) Gb = bf16(Gf)
    cvt_f32_bf16<<<dim3(B * D * D / 4 / 256), 256, 0, stream>>>(
        Gf, Gb, B * D * D / 4);
    // 6) Mt[b] = Gb[b] * Wt^T  (M=N=K=D; 32 blocks, nk=32)
    gemm256<0><<<dim3(D / 256, D / 256, B), 512, 0, stream>>>(
        (const bf16*)Gb, (const bf16*)Wt, Mt, D, D, D, 1,
        (long)D * D, 0, (long)D * D);
    // 7) O[b] = X[b] * Mt[b]^T  (M=4096, N=D, K=D; 128 blocks, nk=32)
    if (bigws) {
        gemm256<2><<<dim3(D / 256, N / 256, B), 512, 0, stream>>>(
            (const bf16*)Xb, (const bf16*)Mt, out, N, D, D, 1,
            (long)N * D, (long)D * D, (long)N * D);
    } else {
        gemm_bt<2, 1, 2><<<dim3(D / 64, N / BM, B), 256, 0, stream>>>(
            (const void*)X, (const bf16*)Mt, out, N, D, D, 1,
            (long)N * D, (long)D * D, (long)N * D);
    }
}

// Round 13
// 192.676 us; speedup vs baseline: 1.0792x; 1.0756x over previous
//
#include <hip/hip_runtime.h>
#include <hip/hip_bf16.h>
#include <stdint.h>

using bf16 = __hip_bfloat16;
typedef __attribute__((ext_vector_type(8))) short short8;
typedef __attribute__((ext_vector_type(4))) float f32x4;

#define BM 128
#define BK 32

// -------- async global->LDS, 16B per lane (m97 pattern) --------
__device__ __forceinline__ void g2lds16(const void* g, void* l) {
    __builtin_amdgcn_global_load_lds(
        (const __attribute__((address_space(1))) void*)g,
        (__attribute__((address_space(3))) void*)l,
        16, 0, 0);
}

template <int N>
__device__ __forceinline__ void s_wait_vmcnt() {
    asm volatile("s_waitcnt vmcnt(%0)" :: "n"(N) : "memory");
}

__device__ __forceinline__ short f2bs(float x) {
    union { bf16 h; short s; } u;
    u.h = __float2bfloat16(x);
    return u.s;
}

// ---- LDS XOR swizzles (conflict-free fragment reads) ----
// bf16 tile [rows][32 bf16] = 4 groups/row of 8 bf16 (16B). s=(row>>1)&3.
__device__ __forceinline__ int bswz(int row, int cg) { return cg ^ ((row >> 1) & 3); }
// fp32 tile [rows][32 f32] = 8 groups/row of 4 f32 (16B). s=row&7.
__device__ __forceinline__ int fswz(int row, int cg) { return cg ^ (row & 7); }

// ---- fp32 -> bf16 64x64 tile transpose (+ optional row-major bf16 copy) ----
__global__ __launch_bounds__(256)
void transpose_cvt(const float* __restrict__ src, ushort* __restrict__ dstT,
                   ushort* __restrict__ dstN,
                   int R, int C, long sstride, long dstrideT, long dstrideN)
{
    __shared__ __align__(16) ushort t[64][72];
    const float* s = src + (size_t)blockIdx.z * sstride;
    ushort*      dT = dstT + (size_t)blockIdx.z * dstrideT;
    const int r0 = blockIdx.y * 64, c0 = blockIdx.x * 64;
    const int tid = threadIdx.x;
#pragma unroll
    for (int ii = 0; ii < 4; ++ii) {
        int idx = ii * 256 + tid;
        int r = idx >> 4, c4 = (idx & 15) * 4;
        float4 v = *(const float4*)&s[(size_t)(r0 + r) * C + c0 + c4];
        union { ushort u[4]; uint2 q; } o;
        o.u[0] = (ushort)f2bs(v.x); o.u[1] = (ushort)f2bs(v.y);
        o.u[2] = (ushort)f2bs(v.z); o.u[3] = (ushort)f2bs(v.w);
        *(uint2*)&t[r][c4] = o.q;
        if (dstN) {
            ushort* dN = dstN + (size_t)blockIdx.z * dstrideN;
            *(uint2*)&dN[(size_t)(r0 + r) * C + c0 + c4] = o.q;
        }
    }
    __syncthreads();
#pragma unroll
    for (int ii = 0; ii < 2; ++ii) {
        int idx = ii * 256 + tid;
        int c = idx >> 3, r8 = (idx & 7) * 8;
        union { ushort u[8]; uint4 v; } tmp;
#pragma unroll
        for (int j = 0; j < 8; ++j) tmp.u[j] = t[r8 + j][c];
        *(uint4*)&dT[(size_t)(c0 + c) * R + r0 + r8] = tmp.v;
    }
}

// -------- fp32 -> bf16 flat convert (4 elems/thread) --------
__global__ __launch_bounds__(256)
void cvt_f32_bf16(const float* __restrict__ in, ushort* __restrict__ out, int n4)
{
    int i = blockIdx.x * 256 + threadIdx.x;
    if (i >= n4) return;
    float4 v = ((const float4*)in)[i];
    union { ushort u[4]; uint2 q; } o;
    o.u[0] = (ushort)f2bs(v.x); o.u[1] = (ushort)f2bs(v.y);
    o.u[2] = (ushort)f2bs(v.z); o.u[3] = (ushort)f2bs(v.w);
    ((uint2*)out)[i] = o.q;
}

// -------- C = A * B^T ; A:[M][K], B:[N][K] row-major, k contiguous --------
// MODE 0: bf16 store. MODE 1: fp32 atomicAdd (split-K). MODE 2: fp32 store.
// A_F32: A operand fp32 in global (staged fp32, cvt at frag load).
// NFRAG: n-fragments (16-wide) per wave; BN = 32*NFRAG.
// R8-measured config (45.0 us steps 4/7): 3-buffer counted-vmcnt pipeline,
// z-aware XCD-contiguous remap (FETCH 65.5 -> 8.2 MB). Unchanged.
template <int MODE, int A_F32, int NFRAG>
__global__ __launch_bounds__(256)
void gemm_bt(const void* __restrict__ Av, const bf16* __restrict__ B,
             void* __restrict__ Cv, int M, int N, int K, int kChunks,
             long sA, long sB, long sC)
{
    constexpr int BN  = 32 * NFRAG;
    constexpr int BSH = (BN * BK * 2) / (256 * 16); // B staging shots
    constexpr int ASH = A_F32 ? 4 : 2;              // A staging shots
    constexpr int L   = ASH + BSH;                  // vmcnt events per stage
    constexpr int ANE = BM * BK * (A_F32 ? 2 : 1);  // bf16 elems per A buffer
    constexpr int BNE = BN * BK;
    __shared__ __align__(16) bf16 lA[3][ANE];
    __shared__ __align__(16) bf16 lB[3][BNE];

    // ---- XCD-contiguous remap (z-aware; bijective since nwg%8==0) ----
    const int gx   = gridDim.x, gy = gridDim.y;
    const int nwg  = gx * gy * gridDim.z;
    const int wgid = (blockIdx.z * gy + blockIdx.y) * gx + blockIdx.x;
    const int lid  = (wgid & 7) * (nwg >> 3) + (wgid >> 3);
    const int pz   = gx * gy;
    const int z    = lid / pz;
    const int rem  = lid - z * pz;
    const int my   = rem / gx;
    const int m0   = my * BM;
    const int n0   = (rem - my * gx) * BN;

    const int batch = z / kChunks;
    const int chunk = z - batch * kChunks;
    const int kLen  = K / kChunks;
    const int k0    = chunk * kLen;

    const int tid  = threadIdx.x;
    const int lane = tid & 63;
    const int wave = tid >> 6;
    const int wr   = wave >> 1, wc = wave & 1;
    const int ml   = lane & 15;
    const int q    = lane >> 4;

    // B staging pointers (swizzled)
    const bf16* Bb = B + (size_t)batch * sB;
    const bf16* bp[BSH];
#pragma unroll
    for (int s = 0; s < BSH; ++s) {
        int idx = s * 256 + tid;
        int row = idx >> 2, cg = idx & 3;
        bp[s] = Bb + (size_t)(n0 + row) * K + k0 + 8 * bswz(row, cg);
    }

    // A staging pointers (swizzled)
    const float* a32[4];
    const bf16*  a16[2];
    if constexpr (A_F32) {
        const float* Ab = (const float*)Av + (size_t)batch * sA;
#pragma unroll
        for (int s = 0; s < 4; ++s) {
            int idx = s * 256 + tid;
            int row = idx >> 3, cg = idx & 7;
            a32[s] = Ab + (size_t)(m0 + row) * K + k0 + 4 * fswz(row, cg);
        }
    } else {
        const bf16* Ab = (const bf16*)Av + (size_t)batch * sA;
#pragma unroll
        for (int s = 0; s < 2; ++s) {
            int idx = s * 256 + tid;
            int row = idx >> 2, cg = idx & 3;
            a16[s] = Ab + (size_t)(m0 + row) * K + k0 + 8 * bswz(row, cg);
        }
    }

    f32x4 acc[4][NFRAG] = {};

    // stage next tile into LDS buffer `buf`, advance pointers by BK
    auto stage = [&](int buf) {
        if constexpr (A_F32) {
            float* lAf = (float*)lA[buf];
#pragma unroll
            for (int s = 0; s < 4; ++s) {
                g2lds16(a32[s], &lAf[(s * 256 + tid) * 4]);
                a32[s] += BK;
            }
        } else {
#pragma unroll
            for (int s = 0; s < 2; ++s) {
                g2lds16(a16[s], &lA[buf][(s * 256 + tid) * 8]);
                a16[s] += BK;
            }
        }
#pragma unroll
        for (int s = 0; s < BSH; ++s) {
            g2lds16(bp[s], &lB[buf][(s * 256 + tid) * 8]);
            bp[s] += BK;
        }
    };

    // read fragments (plain loads; compiler schedules fine lgkm waits vs MFMA)
    auto frags = [&](int buf, short8 (&af)[4], short8 (&bfr)[NFRAG]) {
        const bf16* cA = lA[buf];
        const bf16* cB = lB[buf];
#pragma unroll
        for (int i = 0; i < 4; ++i) {
            const int rA = wr * 64 + i * 16 + ml;
            if constexpr (A_F32) {
                const float* lAf = (const float*)cA;
                float4 x0 = *(const float4*)&lAf[rA * 32 + 4 * fswz(rA, 2 * q)];
                float4 x1 = *(const float4*)&lAf[rA * 32 + 4 * fswz(rA, 2 * q + 1)];
                af[i][0] = f2bs(x0.x); af[i][1] = f2bs(x0.y);
                af[i][2] = f2bs(x0.z); af[i][3] = f2bs(x0.w);
                af[i][4] = f2bs(x1.x); af[i][5] = f2bs(x1.y);
                af[i][6] = f2bs(x1.z); af[i][7] = f2bs(x1.w);
            } else {
                af[i] = *(const short8*)&cA[rA * 32 + 8 * bswz(rA, q)];
            }
        }
#pragma unroll
        for (int j = 0; j < NFRAG; ++j) {
            const int rB = wc * (16 * NFRAG) + j * 16 + ml;
            bfr[j] = *(const short8*)&cB[rB * 32 + 8 * bswz(rB, q)];
        }
    };

    auto mfma = [&](short8 (&af)[4], short8 (&bfr)[NFRAG]) {
#pragma unroll
        for (int mi = 0; mi < 4; ++mi)
#pragma unroll
            for (int nj = 0; nj < NFRAG; ++nj)
                acc[mi][nj] = __builtin_amdgcn_mfma_f32_16x16x32_bf16(
                    af[mi], bfr[nj], acc[mi][nj], 0, 0, 0);
    };

    const int nk = kLen / BK;        // call sites: 16, 32 (all >= 3)
    stage(0); stage(1);              // 2 tiles in flight
    int cur = 0;
    for (int t = 0; t < nk - 2; ++t) {
        s_wait_vmcnt<L>();           // tile t landed; t+1 in flight
        __builtin_amdgcn_s_barrier();
        short8 af_[4], bf_[NFRAG];
        frags(cur, af_, bf_);
        int nb = cur + 2; nb = (nb >= 3) ? nb - 3 : nb;
        stage(nb);                   // tile t+2 -> buf (t+2)%3
        mfma(af_, bf_);
        asm volatile("s_waitcnt lgkmcnt(0)" ::: "memory");
        cur = (cur == 2) ? 0 : cur + 1;
    }
    {   // t = nk-2: tile nk-2 landed, nk-1 in flight
        s_wait_vmcnt<L>();
        __builtin_amdgcn_s_barrier();
        short8 af_[4], bf_[NFRAG];
        frags(cur, af_, bf_);
        mfma(af_, bf_);
        cur = (cur == 2) ? 0 : cur + 1;
    }
    {   // t = nk-1
        s_wait_vmcnt<0>();
        __builtin_amdgcn_s_barrier();
        short8 af_[4], bf_[NFRAG];
        frags(cur, af_, bf_);
        mfma(af_, bf_);
    }

    // epilogue: C/D layout col=lane&15, row=(lane>>4)*4+r (m89-verified)
#pragma unroll
    for (int mi = 0; mi < 4; ++mi)
#pragma unroll
        for (int nj = 0; nj < NFRAG; ++nj)
#pragma unroll
            for (int r = 0; r < 4; ++r) {
                int row = m0 + wr * 64 + mi * 16 + q * 4 + r;
                int col = n0 + wc * (16 * NFRAG) + nj * 16 + ml;
                if constexpr (MODE == 1) {
                    float* Cf = (float*)Cv + (size_t)batch * sC;
                    atomicAdd(&Cf[(size_t)row * N + col], acc[mi][nj][r]);
                } else if constexpr (MODE == 0) {
                    ushort* Cb = (ushort*)Cv + (size_t)batch * sC;
                    Cb[(size_t)row * N + col] = (ushort)f2bs(acc[mi][nj][r]);
                } else {
                    float* Cf = (float*)Cv + (size_t)batch * sC;
                    Cf[(size_t)row * N + col] = acc[mi][nj][r];
                }
            }
}

// ---------------------------------------------------------------
// fp32 I/O.  O = ((X W^T) X^T) X == X * (W^T (X^T X))   [associative]
//   Gf  = Xt * Xt^T    (split-K=4, fp32 atomic)       Xt = bf16(X)^T
//   Mtf = Gf * Wt^T    (batch-merged M=2048, sk=2, fp32 atomic, A fp32)
//   Mt  = bf16(Mtf);  O = X * Mt^T (fp32 store)
// d_out scratch: Xt@0 (16M, dies after Gf) | Gf@16M (8M) | Wt@28M (2M)
//   Mtf@0 (8M) reuses dead Xt space (memset after step 4, stream-ordered)
// ws: [Xb bf16 16M if ws_size>=20M] + Mt bf16 4M.
// Round 12: steps 4/7 = R8's measured-45us config verbatim; step 6
// batch-merged + split-K=2 => 512 blocks (2 blk/CU overlap, ~2x).
// ---------------------------------------------------------------
extern "C" void kernel_launch(void* const* d_in, const int* in_sizes, int n_in,
                              void* d_out, int out_size, void* d_ws, size_t ws_size,
                              hipStream_t stream)
{
    const int B = 2, N = 4096, D = 1024;
    const float* X = (const float*)d_in[0];   // [B][N][D] fp32
    const float* W = (const float*)d_in[1];   // [D][D]    fp32
    float* out = (float*)d_out;               // [B][N][D] fp32

    char* ob = (char*)d_out;
    char* ws = (char*)d_ws;
    ushort* Xt  = (ushort*)ob;                  // [B][D][N] bf16, 16 MiB
    float*  Mtf = (float*)ob;                   // [B][D][D] fp32,  8 MiB (after Xt dies)
    float*  Gf  = (float*)(ob + (16ll << 20));  // [B][D][D] fp32,  8 MiB
    ushort* Wt  = (ushort*)(ob + (28ll << 20)); // [D][D]    bf16,  2 MiB

    const bool bigws = ws_size >= (20ull << 20);
    ushort* Xb = bigws ? (ushort*)ws : nullptr;             // [B][N][D] bf16
    ushort* Mt = (ushort*)(ws + (bigws ? (16ll << 20) : 0)); // [B][D][D] bf16

    // 1) Xt[b] = bf16(X[b])^T  (+ Xb = bf16(X) row-major when ws allows)
    transpose_cvt<<<dim3(D / 64, N / 64, B), 256, 0, stream>>>(
        X, Xt, Xb, N, D, (long)N * D, (long)D * N, (long)N * D);
    // 2) Wt = bf16(W)^T
    transpose_cvt<<<dim3(D / 64, D / 64, 1), 256, 0, stream>>>(
        W, Wt, nullptr, D, D, 0, 0, 0);
    // 3) zero split-K accumulator for Gf
    (void)hipMemsetAsync(Gf, 0, (size_t)B * D * D * sizeof(float), stream);
    // 4) Gf[b] += Xt[b] * Xt[b]^T   (M=N=D, K=4096, sk=4, BN=128;
    //    512 blocks, 2/CU; XCD k owns one (batch,chunk) working set)
    gemm_bt<1, 0, 4><<<dim3(D / 128, D / BM, B * 4), 256, 0, stream>>>(
        (const void*)Xt, (const bf16*)Xt, Gf, D, D, N, 4,
        (long)D * N, (long)D * N, (long)D * D);
    // 5) zero split-K accumulator for Mtf (Xt dead now; stream-ordered)
    (void)hipMemsetAsync(Mtf, 0, (size_t)B * D * D * sizeof(float), stream);
    // 6) Mtf += Gf * Wt^T  — batch-merged: A = Gf as [2048][1024] fp32,
    //    M=2048, N=K=D, sk=2, BN=64 => 16x16x2 = 512 blocks (2/CU)
    gemm_bt<1, 1, 2><<<dim3(D / 64, (B * D) / BM, 2), 256, 0, stream>>>(
        (const void*)Gf, (const bf16*)Wt, Mtf, B * D, D, D, 2,
        0, 0, 0);
    // 6b) Mt = bf16(Mtf)   (8 MB -> 4 MB)
    cvt_f32_bf16<<<dim3(B * D * D / 4 / 256), 256, 0, stream>>>(
        Mtf, Mt, B * D * D / 4);
    // 7) O[b] = X[b] * Mt[b]^T  (M=4096, N=D, K=D, BN=128; 512 blocks)
    if (bigws) {
        gemm_bt<2, 0, 4><<<dim3(D / 128, N / BM, B), 256, 0, stream>>>(
            (const void*)Xb, (const bf16*)Mt, out, N, D, D, 1,
            (long)N * D, (long)D * D, (long)N * D);
    } else {
        gemm_bt<2, 1, 4><<<dim3(D / 128, N / BM, B), 256, 0, stream>>>(
            (const void*)X, (const bf16*)Mt, out, N, D, D, 1,
            (long)N * D, (long)D * D, (long)N * D);
    }
}